// Round 2
// baseline (1126.608 us; speedup 1.0000x reference)
//
#include <hip/hip_runtime.h>
#include <hip/hip_cooperative_groups.h>

namespace cg = cooperative_groups;

#define N_NODES 50000
#define DIM 128
#define N_EDGES 625000
#define NBLK 196   // ceil(N/256) scan blocks
#define EBLK 2442  // ceil(E/256) edge blocks
#define GBLK 1024  // cooperative grid: 4 blocks/CU x 256 CUs

// fallback k_setup grid partition
#define SC_BLOCKS 12500           // scales/tangents: 16 rows/block over 4N rows
#define PK_BLOCKS 256             // W-pack: 65536 elems
#define ZR_BLOCKS 391             // zero deg+cursor: 100,000 ints
#define SETUP_BLOCKS (SC_BLOCKS + PK_BLOCKS + ZR_BLOCKS)

typedef float f32x4 __attribute__((ext_vector_type(4)));
typedef short s16x8 __attribute__((ext_vector_type(8)));

union U8 { unsigned short us[8]; uint4 v; };

__device__ __forceinline__ unsigned short f2bf(float f) {
    unsigned u = __builtin_bit_cast(unsigned, f);
    unsigned r = (u + 0x7fffu + ((u >> 16) & 1u)) >> 16;  // RNE
    return (unsigned short)r;
}
__device__ __forceinline__ float lo_bf(unsigned u) {
    return __builtin_bit_cast(float, u << 16);
}
__device__ __forceinline__ float hi_bf(unsigned u) {
    return __builtin_bit_cast(float, u & 0xffff0000u);
}

// async global->LDS, 16 B per lane; lds dest = uniform base + lane*16 (m104)
__device__ __forceinline__ void gload_lds16(const unsigned short* g, unsigned short* l) {
    __builtin_amdgcn_global_load_lds(
        (const __attribute__((address_space(1))) void*)g,
        (__attribute__((address_space(3))) void*)l, 16, 0, 0);
}

// logmap0 scale factor for one row given sum-of-squares reduced across group
__device__ __forceinline__ float logmap_scale(float ss, float sc) {
    float xn = fmaxf(sqrtf(ss), 1e-15f);
    float arg = fminf(sc * xn, 1.0f - 1e-5f);
    // s = artanh(arg)/(sc*xn); for arg<0.25 the clip is inactive so the
    // division cancels: artanh(z)/z = 1 + z^2/3 + z^4/5 + z^6/7 (rel err ~2e-6)
    if (arg < 0.25f) {
        float z2 = arg * arg;
        return 1.0f + z2 * (0.33333333f + z2 * (0.2f + z2 * 0.14285715f));
    }
    float at = 0.5f * log1pf(2.0f * arg / (1.0f - arg));
    return at / (sc * xn);
}

// ==================================================================
// Cooperative mega-kernel: zero + pack + logmap-scale | hist | scan |
// bucket | gather — one launch, grid.sync between dependent phases.
// ==================================================================
__global__ __launch_bounds__(256, 4) void k_graph(
    const float* __restrict__ node, const float* __restrict__ h1,
    const float* __restrict__ h2, const float* __restrict__ h3,
    const float* __restrict__ lin_w, const float* __restrict__ conv_w,
    const float* __restrict__ curv,
    const int* __restrict__ esrc, const int* __restrict__ edst,
    unsigned short* __restrict__ node_t, unsigned short* __restrict__ A,
    unsigned short* __restrict__ Wt,
    int* __restrict__ deg, int* __restrict__ cursor,
    int* __restrict__ rowstart, int* __restrict__ csr_src,
    int* __restrict__ blocksum) {
    cg::grid_group grid = cg::this_grid();
    __shared__ int sm[256];
    __shared__ int bsl[256];
    int tid = threadIdx.x;
    int b = blockIdx.x;
    int gtid = b * 256 + tid;

    // ---- P0a: zero deg + cursor (adjacent: 100,000 ints from deg) ----
    for (int i = gtid; i < 100000; i += GBLK * 256) deg[i] = 0;

    // ---- P0b: pack Wt[o][k] bf16 ----
    for (int idx = gtid; idx < 65536; idx += GBLK * 256) {
        int o = idx >> 9;
        int k = idx & 511;
        float v;
        if (k < 128) {
            v = lin_w[o * 128 + k];
        } else {
            int kk = (k - 128) >> 7;
            int i = (k - 128) & 127;
            v = conv_w[o * 384 + i * 3 + kk];
        }
        Wt[idx] = f2bf(v);
    }

    // ---- P0c: logmap0 scale of node + 3 hists (4N rows, 16 lanes/row) ----
    {
        float c = fabsf(curv[0]);
        float sc = sqrtf(c);
        int g = tid & 15;
        for (int row = b * 16 + (tid >> 4); row < 4 * N_NODES; row += GBLK * 16) {
            int a = row / N_NODES;
            int n = row - a * N_NODES;
            const float* src = (a == 0) ? node : (a == 1) ? h1 : (a == 2) ? h2 : h3;
            const float4* p = (const float4*)&src[n * DIM + g * 8];
            float4 x0 = p[0], x1 = p[1];
            float ss = x0.x * x0.x + x0.y * x0.y + x0.z * x0.z + x0.w * x0.w
                     + x1.x * x1.x + x1.y * x1.y + x1.z * x1.z + x1.w * x1.w;
            ss += __shfl_xor(ss, 1, 64);
            ss += __shfl_xor(ss, 2, 64);
            ss += __shfl_xor(ss, 4, 64);
            ss += __shfl_xor(ss, 8, 64);  // 16-lane group reduction
            float s = logmap_scale(ss, sc);
            U8 u;
            u.us[0] = f2bf(x0.x * s); u.us[1] = f2bf(x0.y * s);
            u.us[2] = f2bf(x0.z * s); u.us[3] = f2bf(x0.w * s);
            u.us[4] = f2bf(x1.x * s); u.us[5] = f2bf(x1.y * s);
            u.us[6] = f2bf(x1.z * s); u.us[7] = f2bf(x1.w * s);
            if (a == 0) {
                *(uint4*)&node_t[n * DIM + g * 8] = u.v;
            } else {
                *(uint4*)&A[n * 512 + a * 128 + g * 8] = u.v;
            }
        }
    }
    __threadfence();
    grid.sync();

    // ---- P1: degree histogram ----
    for (int e = gtid; e < N_EDGES; e += GBLK * 256)
        __hip_atomic_fetch_add(&deg[edst[e]], 1, __ATOMIC_RELAXED, __HIP_MEMORY_SCOPE_AGENT);
    __threadfence();
    grid.sync();

    // ---- P2: per-256-chunk exclusive scan (blocks 0..NBLK-1) ----
    if (b < NBLK) {
        int i = b * 256 + tid;
        int v = (i < N_NODES) ? deg[i] : 0;
        sm[tid] = v;
        __syncthreads();
        #pragma unroll
        for (int off = 1; off < 256; off <<= 1) {
            int x = (tid >= off) ? sm[tid - off] : 0;
            __syncthreads();
            sm[tid] += x;
            __syncthreads();
        }
        if (i < N_NODES) rowstart[i] = sm[tid] - v;
        if (tid == 255) blocksum[b] = sm[tid];
    }
    __threadfence();
    grid.sync();

    // ---- P3: per-block replica of chunk-total exclusive scan -> LDS ----
    {
        int v = (tid < NBLK) ? blocksum[tid] : 0;
        sm[tid] = v;
        __syncthreads();
        #pragma unroll
        for (int off = 1; off < 256; off <<= 1) {
            int x = (tid >= off) ? sm[tid - off] : 0;
            __syncthreads();
            sm[tid] += x;
            __syncthreads();
        }
        bsl[tid] = sm[tid] - v;  // exclusive prefix of chunk totals
        __syncthreads();
    }

    // ---- P4: bucket edge sources by destination (CSR fill) ----
    for (int e = gtid; e < N_EDGES; e += GBLK * 256) {
        int d = edst[e];
        int pos = __hip_atomic_fetch_add(&cursor[d], 1, __ATOMIC_RELAXED, __HIP_MEMORY_SCOPE_AGENT);
        csr_src[rowstart[d] + bsl[d >> 8] + pos] = esrc[e];
    }
    __threadfence();
    grid.sync();

    // ---- P5: gather: A[n][0:128] = bf16(avg of node_t rows in CSR row n) ----
    {
        int wv = b * 4 + (tid >> 6);
        int lane = tid & 63;
        for (int n = wv; n < N_NODES; n += GBLK * 4) {
            int begin = rowstart[n] + bsl[n >> 8];
            int cnt = deg[n];
            float a0 = 0.f, a1 = 0.f, b0 = 0.f, b1 = 0.f;
            float c0 = 0.f, c1 = 0.f, d0 = 0.f, d1 = 0.f;
            for (int base = 0; base < cnt; base += 64) {
                int rem = cnt - base;
                int m = rem < 64 ? rem : 64;
                int my = csr_src[begin + base + (lane < m ? lane : m - 1)];
                for (int i = 0; i < m; i += 8) {
                    // masked parallel batch of 8: all loads issued (clamped
                    // index), out-of-range contributions predicated to 0 —
                    // kills the serial dependent-load tail (avg deg = 12.5).
                    int i1 = i + 1 < m ? i + 1 : m - 1;
                    int i2 = i + 2 < m ? i + 2 : m - 1;
                    int i3 = i + 3 < m ? i + 3 : m - 1;
                    int i4 = i + 4 < m ? i + 4 : m - 1;
                    int i5 = i + 5 < m ? i + 5 : m - 1;
                    int i6 = i + 6 < m ? i + 6 : m - 1;
                    int i7 = i + 7 < m ? i + 7 : m - 1;
                    int s0 = __shfl(my, i, 64),  s1 = __shfl(my, i1, 64);
                    int s2 = __shfl(my, i2, 64), s3 = __shfl(my, i3, 64);
                    int s4 = __shfl(my, i4, 64), s5 = __shfl(my, i5, 64);
                    int s6 = __shfl(my, i6, 64), s7 = __shfl(my, i7, 64);
                    unsigned u0 = *(const unsigned*)&node_t[s0 * DIM + lane * 2];
                    unsigned u1 = *(const unsigned*)&node_t[s1 * DIM + lane * 2];
                    unsigned u2 = *(const unsigned*)&node_t[s2 * DIM + lane * 2];
                    unsigned u3 = *(const unsigned*)&node_t[s3 * DIM + lane * 2];
                    unsigned u4 = *(const unsigned*)&node_t[s4 * DIM + lane * 2];
                    unsigned u5 = *(const unsigned*)&node_t[s5 * DIM + lane * 2];
                    unsigned u6 = *(const unsigned*)&node_t[s6 * DIM + lane * 2];
                    unsigned u7 = *(const unsigned*)&node_t[s7 * DIM + lane * 2];
                    a0 += lo_bf(u0); a1 += hi_bf(u0);
                    b0 += (i + 1 < m) ? lo_bf(u1) : 0.f; b1 += (i + 1 < m) ? hi_bf(u1) : 0.f;
                    c0 += (i + 2 < m) ? lo_bf(u2) : 0.f; c1 += (i + 2 < m) ? hi_bf(u2) : 0.f;
                    d0 += (i + 3 < m) ? lo_bf(u3) : 0.f; d1 += (i + 3 < m) ? hi_bf(u3) : 0.f;
                    a0 += (i + 4 < m) ? lo_bf(u4) : 0.f; a1 += (i + 4 < m) ? hi_bf(u4) : 0.f;
                    b0 += (i + 5 < m) ? lo_bf(u5) : 0.f; b1 += (i + 5 < m) ? hi_bf(u5) : 0.f;
                    c0 += (i + 6 < m) ? lo_bf(u6) : 0.f; c1 += (i + 6 < m) ? hi_bf(u6) : 0.f;
                    d0 += (i + 7 < m) ? lo_bf(u7) : 0.f; d1 += (i + 7 < m) ? hi_bf(u7) : 0.f;
                }
            }
            float t0 = (a0 + b0) + (c0 + d0);
            float t1 = (a1 + b1) + (c1 + d1);
            float inv = (cnt > 0) ? 1.0f / (float)cnt : 0.0f;
            unsigned short o0 = f2bf(t0 * inv), o1 = f2bf(t1 * inv);
            *(unsigned*)&A[n * 512 + lane * 2] = (unsigned)o0 | ((unsigned)o1 << 16);
        }
    }
}

// ==================================================================
// Fallback chain (used only if cooperative launch is rejected)
// ==================================================================
__global__ __launch_bounds__(256) void k_setup(
    const float* __restrict__ node, const float* __restrict__ h1,
    const float* __restrict__ h2, const float* __restrict__ h3,
    const float* __restrict__ lin_w, const float* __restrict__ conv_w,
    const float* __restrict__ curv,
    unsigned short* __restrict__ node_t, unsigned short* __restrict__ A,
    unsigned short* __restrict__ Wt, int* __restrict__ zero_base) {
    int b = blockIdx.x;
    int tid = threadIdx.x;
    if (b < SC_BLOCKS) {
        int row = b * 16 + (tid >> 4);
        int g = tid & 15;
        int a = row / N_NODES;
        int n = row - a * N_NODES;
        const float* src = (a == 0) ? node : (a == 1) ? h1 : (a == 2) ? h2 : h3;
        const float4* p = (const float4*)&src[n * DIM + g * 8];
        float4 x0 = p[0], x1 = p[1];
        float ss = x0.x * x0.x + x0.y * x0.y + x0.z * x0.z + x0.w * x0.w
                 + x1.x * x1.x + x1.y * x1.y + x1.z * x1.z + x1.w * x1.w;
        ss += __shfl_xor(ss, 1, 64);
        ss += __shfl_xor(ss, 2, 64);
        ss += __shfl_xor(ss, 4, 64);
        ss += __shfl_xor(ss, 8, 64);
        float c = fabsf(curv[0]);
        float s = logmap_scale(ss, sqrtf(c));
        U8 u;
        u.us[0] = f2bf(x0.x * s); u.us[1] = f2bf(x0.y * s);
        u.us[2] = f2bf(x0.z * s); u.us[3] = f2bf(x0.w * s);
        u.us[4] = f2bf(x1.x * s); u.us[5] = f2bf(x1.y * s);
        u.us[6] = f2bf(x1.z * s); u.us[7] = f2bf(x1.w * s);
        if (a == 0) {
            *(uint4*)&node_t[n * DIM + g * 8] = u.v;
        } else {
            *(uint4*)&A[n * 512 + a * 128 + g * 8] = u.v;
        }
    } else if (b < SC_BLOCKS + PK_BLOCKS) {
        int idx = (b - SC_BLOCKS) * 256 + tid;
        int o = idx >> 9;
        int k = idx & 511;
        float v;
        if (k < 128) {
            v = lin_w[o * 128 + k];
        } else {
            int kk = (k - 128) >> 7;
            int i = (k - 128) & 127;
            v = conv_w[o * 384 + i * 3 + kk];
        }
        Wt[idx] = f2bf(v);
    } else {
        int i = (b - SC_BLOCKS - PK_BLOCKS) * 256 + tid;
        if (i < 100000) zero_base[i] = 0;
    }
}

__global__ void k_hist(const int* __restrict__ edst, int* __restrict__ deg) {
    int e = blockIdx.x * 256 + threadIdx.x;
    if (e < N_EDGES)
        __hip_atomic_fetch_add(&deg[edst[e]], 1, __ATOMIC_RELAXED, __HIP_MEMORY_SCOPE_AGENT);
}

__global__ void k_scan1(const int* __restrict__ deg, int* __restrict__ rowstart,
                        int* __restrict__ blocksum) {
    __shared__ int sm[256];
    int t = threadIdx.x;
    int i = blockIdx.x * 256 + t;
    int v = (i < N_NODES) ? deg[i] : 0;
    sm[t] = v;
    __syncthreads();
    #pragma unroll
    for (int off = 1; off < 256; off <<= 1) {
        int x = (t >= off) ? sm[t - off] : 0;
        __syncthreads();
        sm[t] += x;
        __syncthreads();
    }
    if (i < N_NODES) rowstart[i] = sm[t] - v;
    if (t == 255) blocksum[blockIdx.x] = sm[t];
}

__global__ void k_scan2(int* __restrict__ blocksum) {
    __shared__ int sm[256];
    int t = threadIdx.x;
    int v = (t < NBLK) ? blocksum[t] : 0;
    sm[t] = v;
    __syncthreads();
    #pragma unroll
    for (int off = 1; off < 256; off <<= 1) {
        int x = (t >= off) ? sm[t - off] : 0;
        __syncthreads();
        sm[t] += x;
        __syncthreads();
    }
    if (t < NBLK) blocksum[t] = sm[t] - v;
}

__global__ void k_bucket(const int* __restrict__ esrc, const int* __restrict__ edst,
                         const int* __restrict__ rowstart, const int* __restrict__ blocksum,
                         int* __restrict__ cursor, int* __restrict__ csr_src) {
    int e = blockIdx.x * 256 + threadIdx.x;
    if (e >= N_EDGES) return;
    int d = edst[e];
    int pos = __hip_atomic_fetch_add(&cursor[d], 1, __ATOMIC_RELAXED, __HIP_MEMORY_SCOPE_AGENT);
    csr_src[rowstart[d] + blocksum[d >> 8] + pos] = esrc[e];
}

__global__ __launch_bounds__(256) void k_gather(
    const int* __restrict__ csr_src, const int* __restrict__ rowstart,
    const int* __restrict__ blocksum, const int* __restrict__ deg,
    const unsigned short* __restrict__ node_t, unsigned short* __restrict__ A) {
    int n = blockIdx.x * 4 + (threadIdx.x >> 6);
    int lane = threadIdx.x & 63;
    int begin = rowstart[n] + blocksum[n >> 8];
    int cnt = deg[n];
    float a0 = 0.f, a1 = 0.f, b0 = 0.f, b1 = 0.f;
    float c0 = 0.f, c1 = 0.f, d0 = 0.f, d1 = 0.f;
    for (int base = 0; base < cnt; base += 64) {
        int rem = cnt - base;
        int m = rem < 64 ? rem : 64;
        int my = csr_src[begin + base + (lane < m ? lane : m - 1)];
        for (int i = 0; i < m; i += 8) {
            int i1 = i + 1 < m ? i + 1 : m - 1;
            int i2 = i + 2 < m ? i + 2 : m - 1;
            int i3 = i + 3 < m ? i + 3 : m - 1;
            int i4 = i + 4 < m ? i + 4 : m - 1;
            int i5 = i + 5 < m ? i + 5 : m - 1;
            int i6 = i + 6 < m ? i + 6 : m - 1;
            int i7 = i + 7 < m ? i + 7 : m - 1;
            int s0 = __shfl(my, i, 64),  s1 = __shfl(my, i1, 64);
            int s2 = __shfl(my, i2, 64), s3 = __shfl(my, i3, 64);
            int s4 = __shfl(my, i4, 64), s5 = __shfl(my, i5, 64);
            int s6 = __shfl(my, i6, 64), s7 = __shfl(my, i7, 64);
            unsigned u0 = *(const unsigned*)&node_t[s0 * DIM + lane * 2];
            unsigned u1 = *(const unsigned*)&node_t[s1 * DIM + lane * 2];
            unsigned u2 = *(const unsigned*)&node_t[s2 * DIM + lane * 2];
            unsigned u3 = *(const unsigned*)&node_t[s3 * DIM + lane * 2];
            unsigned u4 = *(const unsigned*)&node_t[s4 * DIM + lane * 2];
            unsigned u5 = *(const unsigned*)&node_t[s5 * DIM + lane * 2];
            unsigned u6 = *(const unsigned*)&node_t[s6 * DIM + lane * 2];
            unsigned u7 = *(const unsigned*)&node_t[s7 * DIM + lane * 2];
            a0 += lo_bf(u0); a1 += hi_bf(u0);
            b0 += (i + 1 < m) ? lo_bf(u1) : 0.f; b1 += (i + 1 < m) ? hi_bf(u1) : 0.f;
            c0 += (i + 2 < m) ? lo_bf(u2) : 0.f; c1 += (i + 2 < m) ? hi_bf(u2) : 0.f;
            d0 += (i + 3 < m) ? lo_bf(u3) : 0.f; d1 += (i + 3 < m) ? hi_bf(u3) : 0.f;
            a0 += (i + 4 < m) ? lo_bf(u4) : 0.f; a1 += (i + 4 < m) ? hi_bf(u4) : 0.f;
            b0 += (i + 5 < m) ? lo_bf(u5) : 0.f; b1 += (i + 5 < m) ? hi_bf(u5) : 0.f;
            c0 += (i + 6 < m) ? lo_bf(u6) : 0.f; c1 += (i + 6 < m) ? hi_bf(u6) : 0.f;
            d0 += (i + 7 < m) ? lo_bf(u7) : 0.f; d1 += (i + 7 < m) ? hi_bf(u7) : 0.f;
        }
    }
    float t0 = (a0 + b0) + (c0 + d0);
    float t1 = (a1 + b1) + (c1 + d1);
    float inv = (cnt > 0) ? 1.0f / (float)cnt : 0.0f;
    unsigned short o0 = f2bf(t0 * inv), o1 = f2bf(t1 * inv);
    *(unsigned*)&A[n * 512 + lane * 2] = (unsigned)o0 | ((unsigned)o1 << 16);
}

// ---- K6: [N x 512] @ [512 x 128] bf16 MFMA GEMM + expmap0 epilogue ----
// BK=64 double-buffered 2-phase pipeline (T3 minimum template).
#define RB 64
#define BK 64
__global__ __launch_bounds__(256) void k_gemm(
    const unsigned short* __restrict__ A, const int* __restrict__ deg,
    const unsigned short* __restrict__ Wt,  // [128][512] bf16
    const float* __restrict__ lin_b, const float* __restrict__ conv_b,
    const float* __restrict__ curv, float* __restrict__ out) {
    __shared__ __align__(16) unsigned short As[2][RB * BK];    // 8 KB each
    __shared__ __align__(16) unsigned short Bs[2][128 * BK];   // 16 KB each
    int tid = threadIdx.x;
    int n0 = blockIdx.x * RB;
    int w = tid >> 6;
    int lane = tid & 63;
    int ml = lane & 15;
    int q = lane >> 4;
    int lr = lane >> 3;      // row-within-8 for staging
    int lj = lane & 7;       // 16B-chunk-within-row for staging

    f32x4 acc[8];
    #pragma unroll
    for (int i = 0; i < 8; ++i) acc[i] = (f32x4){0.f, 0.f, 0.f, 0.f};

    // prologue: stage chunk 0 into buffer 0
    #pragma unroll
    for (int t = 0; t < 2; ++t) {
        int m = t * 4 + w;
        int r = m * 8 + lr;
        int jg = lj ^ (r & 7);
        gload_lds16(A + (n0 + r) * 512 + jg * 8, &As[0][m * 512]);
    }
    #pragma unroll
    for (int t = 0; t < 4; ++t) {
        int m = t * 4 + w;
        int r = m * 8 + lr;
        int jg = lj ^ (r & 7);
        gload_lds16(Wt + r * 512 + jg * 8, &Bs[0][m * 512]);
    }

    #pragma unroll
    for (int kk = 0; kk < 8; ++kk) {
        int cur = kk & 1;
        __syncthreads();  // drains stage-kk loads; all waves done with other buf
        if (kk < 7) {
            int nb = cur ^ 1;
            #pragma unroll
            for (int t = 0; t < 2; ++t) {
                int m = t * 4 + w;
                int r = m * 8 + lr;
                int jg = lj ^ (r & 7);
                gload_lds16(A + (n0 + r) * 512 + (kk + 1) * 64 + jg * 8, &As[nb][m * 512]);
            }
            #pragma unroll
            for (int t = 0; t < 4; ++t) {
                int m = t * 4 + w;
                int r = m * 8 + lr;
                int jg = lj ^ (r & 7);
                gload_lds16(Wt + r * 512 + (kk + 1) * 64 + jg * 8, &Bs[nb][m * 512]);
            }
        }
        __builtin_amdgcn_s_setprio(1);
        #pragma unroll
        for (int ks = 0; ks < 2; ++ks) {
            int ca = ((ks * 4 + q) ^ (ml & 7)) * 8;
            s16x8 a = *(const s16x8*)&As[cur][(w * 16 + ml) * BK + ca];
            #pragma unroll
            for (int ct = 0; ct < 8; ++ct) {
                s16x8 bb = *(const s16x8*)&Bs[cur][(ct * 16 + ml) * BK + ca];
                acc[ct] = __builtin_amdgcn_mfma_f32_16x16x32_bf16(a, bb, acc[ct], 0, 0, 0);
            }
        }
        __builtin_amdgcn_s_setprio(0);
    }

    float c = fabsf(curv[0]);
    float sc = sqrtf(c);
    float cb[8], lb[8];
    #pragma unroll
    for (int ct = 0; ct < 8; ++ct) {
        cb[ct] = conv_b[ct * 16 + ml];
        lb[ct] = lin_b[ct * 16 + ml];
    }
    #pragma unroll
    for (int r = 0; r < 4; ++r) {
        int n = n0 + w * 16 + q * 4 + r;  // D-frag: row = quad*4 + reg, col = lane&15
        bool valid = (n < N_NODES);
        float dgf = 0.f;
        if (valid) dgf = (deg[n] > 0) ? 1.0f : 0.0f;
        float y[8];
        float ssq = 0.f;
        #pragma unroll
        for (int ct = 0; ct < 8; ++ct) {
            float v = acc[ct][r] + cb[ct] + dgf * lb[ct];
            y[ct] = v;
            ssq += v * v;
        }
        ssq += __shfl_xor(ssq, 1, 64);
        ssq += __shfl_xor(ssq, 2, 64);
        ssq += __shfl_xor(ssq, 4, 64);
        ssq += __shfl_xor(ssq, 8, 64);
        float un = fmaxf(sqrtf(ssq), 1e-15f);
        float z = sc * un;
        float os;
        if (z < 0.25f) {
            float z2 = z * z;
            os = 1.0f + z2 * (-0.33333333f + z2 * (0.13333333f - z2 * 0.053968254f));
        } else {
            os = tanhf(z) / z;
        }
        if (valid) {
            #pragma unroll
            for (int ct = 0; ct < 8; ++ct)
                out[n * DIM + ct * 16 + ml] = y[ct] * os;  // f32 output
        }
    }
}

extern "C" void kernel_launch(void* const* d_in, const int* in_sizes, int n_in,
                              void* d_out, int out_size, void* d_ws, size_t ws_size,
                              hipStream_t stream) {
    (void)in_sizes; (void)n_in; (void)out_size; (void)ws_size;
    const float* node   = (const float*)d_in[0];
    const float* h1     = (const float*)d_in[1];
    const float* h2     = (const float*)d_in[2];
    const float* h3     = (const float*)d_in[3];
    const float* lin_w  = (const float*)d_in[4];
    const float* lin_b  = (const float*)d_in[5];
    const float* conv_w = (const float*)d_in[6];
    const float* conv_b = (const float*)d_in[7];
    const float* curv   = (const float*)d_in[8];
    const int* esrc = (const int*)d_in[9];
    const int* edst = (const int*)d_in[10];
    float* out = (float*)d_out;

    // ws layout (bytes):
    //   [0, 51,249,152)           A        bf16 [50048][512]
    //   [51,249,152, 64,049,152)  node_t   bf16 [N][128]
    //   [64,049,152, 64,180,224)  Wt       bf16 [128][512]
    //   [64,180,224, 64,380,224)  deg      i32 [N]   } adjacent for fused zero
    //   [64,380,224, 64,580,224)  cursor   i32 [N]   }
    //   [64,580,224, 64,780,224)  rowstart i32 [N]
    //   [64,780,224, 67,280,224)  csr_src  i32 [E]
    //   [67,280,224, 67,281,248)  blocksum i32 [256]
    char* ws = (char*)d_ws;
    unsigned short* A = (unsigned short*)ws;
    unsigned short* node_t = (unsigned short*)(ws + 51249152);
    unsigned short* Wt = (unsigned short*)(ws + 64049152);
    int* deg = (int*)(ws + 64180224);
    int* cursor = (int*)(ws + 64380224);
    int* rowstart = (int*)(ws + 64580224);
    int* csr_src = (int*)(ws + 64780224);
    int* blocksum = (int*)(ws + 67280224);

    void* kargs[] = {
        (void*)&node, (void*)&h1, (void*)&h2, (void*)&h3,
        (void*)&lin_w, (void*)&conv_w, (void*)&curv,
        (void*)&esrc, (void*)&edst,
        (void*)&node_t, (void*)&A, (void*)&Wt,
        (void*)&deg, (void*)&cursor, (void*)&rowstart,
        (void*)&csr_src, (void*)&blocksum,
    };
    hipError_t err = hipLaunchCooperativeKernel(
        (const void*)k_graph, dim3(GBLK), dim3(256), kargs, 0, stream);
    if (err != hipSuccess) {
        // fallback: original 6-kernel chain
        hipLaunchKernelGGL(k_setup, dim3(SETUP_BLOCKS), dim3(256), 0, stream,
                           node, h1, h2, h3, lin_w, conv_w, curv, node_t, A, Wt, deg);
        hipLaunchKernelGGL(k_hist, dim3(EBLK), dim3(256), 0, stream, edst, deg);
        hipLaunchKernelGGL(k_scan1, dim3(NBLK), dim3(256), 0, stream, deg, rowstart, blocksum);
        hipLaunchKernelGGL(k_scan2, dim3(1), dim3(256), 0, stream, blocksum);
        hipLaunchKernelGGL(k_bucket, dim3(EBLK), dim3(256), 0, stream,
                           esrc, edst, rowstart, blocksum, cursor, csr_src);
        hipLaunchKernelGGL(k_gather, dim3(12500), dim3(256), 0, stream,
                           csr_src, rowstart, blocksum, deg, node_t, A);
    }
    hipLaunchKernelGGL(k_gemm, dim3((N_NODES + RB - 1) / RB), dim3(256), 0, stream,
                       A, deg, Wt, lin_b, conv_b, curv, out);
}

// Round 3
// 281.521 us; speedup vs baseline: 4.0019x; 4.0019x over previous
//
#include <hip/hip_runtime.h>

#define N_NODES 50000
#define DIM 128
#define N_EDGES 625000
#define NBLK 196   // ceil(N/256) scan blocks
#define EBLK 2442  // ceil(E/256) edge blocks

// k_setup_hist grid partition
#define SC_BLOCKS 12500           // scales/tangents: 16 rows/block over 4N rows
#define PK_BLOCKS 256             // W-pack: 65536 elems
#define SH_BLOCKS (SC_BLOCKS + PK_BLOCKS + EBLK)

typedef float f32x4 __attribute__((ext_vector_type(4)));
typedef short s16x8 __attribute__((ext_vector_type(8)));

union U8 { unsigned short us[8]; uint4 v; };

__device__ __forceinline__ unsigned short f2bf(float f) {
    unsigned u = __builtin_bit_cast(unsigned, f);
    unsigned r = (u + 0x7fffu + ((u >> 16) & 1u)) >> 16;  // RNE
    return (unsigned short)r;
}
__device__ __forceinline__ float lo_bf(unsigned u) {
    return __builtin_bit_cast(float, u << 16);
}
__device__ __forceinline__ float hi_bf(unsigned u) {
    return __builtin_bit_cast(float, u & 0xffff0000u);
}

// async global->LDS, 16 B per lane; lds dest = uniform base + lane*16 (m104)
__device__ __forceinline__ void gload_lds16(const unsigned short* g, unsigned short* l) {
    __builtin_amdgcn_global_load_lds(
        (const __attribute__((address_space(1))) void*)g,
        (__attribute__((address_space(3))) void*)l, 16, 0, 0);
}

// logmap0 scale factor for one row given sum-of-squares reduced across group
__device__ __forceinline__ float logmap_scale(float ss, float sc) {
    float xn = fmaxf(sqrtf(ss), 1e-15f);
    float arg = fminf(sc * xn, 1.0f - 1e-5f);
    // s = artanh(arg)/(sc*xn); for arg<0.25 the clip is inactive so the
    // division cancels: artanh(z)/z = 1 + z^2/3 + z^4/5 + z^6/7 (rel err ~2e-6)
    if (arg < 0.25f) {
        float z2 = arg * arg;
        return 1.0f + z2 * (0.33333333f + z2 * (0.2f + z2 * 0.14285715f));
    }
    float at = 0.5f * log1pf(2.0f * arg / (1.0f - arg));
    return at / (sc * xn);
}

// ---- K0: zero deg[50k] + cursor[50k] + done[1] (adjacent ints) ----
__global__ __launch_bounds__(256) void k_zero(int* __restrict__ zero_base) {
    int i = blockIdx.x * 256 + threadIdx.x;
    if (i < 100001) zero_base[i] = 0;
}

// ---- K1: fused setup + pack + edge histogram ----
// blocks [0, SC): logmap0 per-row scale; a==0 -> node_t = bf16(scale*node);
//                 a>0 -> A[n][a*128..] = bf16(scale*h_a)  (pre-packed GEMM A)
// blocks [SC, SC+PK): pack Wt[o][k] bf16
// blocks [SC+PK, ...): degree histogram (deg zeroed by prior k_zero launch)
__global__ __launch_bounds__(256) void k_setup_hist(
    const float* __restrict__ node, const float* __restrict__ h1,
    const float* __restrict__ h2, const float* __restrict__ h3,
    const float* __restrict__ lin_w, const float* __restrict__ conv_w,
    const float* __restrict__ curv, const int* __restrict__ edst,
    unsigned short* __restrict__ node_t, unsigned short* __restrict__ A,
    unsigned short* __restrict__ Wt, int* __restrict__ deg) {
    int b = blockIdx.x;
    int tid = threadIdx.x;
    if (b < SC_BLOCKS) {
        int row = b * 16 + (tid >> 4);  // [0, 4N); matrix index uniform per block
        int g = tid & 15;
        int a = row / N_NODES;
        int n = row - a * N_NODES;
        const float* src = (a == 0) ? node : (a == 1) ? h1 : (a == 2) ? h2 : h3;
        const float4* p = (const float4*)&src[n * DIM + g * 8];
        float4 x0 = p[0], x1 = p[1];
        float ss = x0.x * x0.x + x0.y * x0.y + x0.z * x0.z + x0.w * x0.w
                 + x1.x * x1.x + x1.y * x1.y + x1.z * x1.z + x1.w * x1.w;
        ss += __shfl_xor(ss, 1, 64);
        ss += __shfl_xor(ss, 2, 64);
        ss += __shfl_xor(ss, 4, 64);
        ss += __shfl_xor(ss, 8, 64);  // 16-lane group reduction
        float c = fabsf(curv[0]);
        float s = logmap_scale(ss, sqrtf(c));
        U8 u;
        u.us[0] = f2bf(x0.x * s); u.us[1] = f2bf(x0.y * s);
        u.us[2] = f2bf(x0.z * s); u.us[3] = f2bf(x0.w * s);
        u.us[4] = f2bf(x1.x * s); u.us[5] = f2bf(x1.y * s);
        u.us[6] = f2bf(x1.z * s); u.us[7] = f2bf(x1.w * s);
        if (a == 0) {  // branch uniform per block
            *(uint4*)&node_t[n * DIM + g * 8] = u.v;
        } else {
            *(uint4*)&A[n * 512 + a * 128 + g * 8] = u.v;
        }
    } else if (b < SC_BLOCKS + PK_BLOCKS) {
        int idx = (b - SC_BLOCKS) * 256 + tid;  // 65536
        int o = idx >> 9;
        int k = idx & 511;
        float v;
        if (k < 128) {
            v = lin_w[o * 128 + k];
        } else {
            int kk = (k - 128) >> 7;
            int i = (k - 128) & 127;
            v = conv_w[o * 384 + i * 3 + kk];
        }
        Wt[idx] = f2bf(v);
    } else {
        int e = (b - SC_BLOCKS - PK_BLOCKS) * 256 + tid;
        if (e < N_EDGES)
            __hip_atomic_fetch_add(&deg[edst[e]], 1, __ATOMIC_RELAXED,
                                   __HIP_MEMORY_SCOPE_AGENT);
    }
}

// ---- K2: per-256-chunk exclusive scan; last block scans chunk totals ----
// (decoupled last-block pattern: no spin — non-last blocks exit)
__global__ __launch_bounds__(256) void k_scan12(
    const int* __restrict__ deg, int* __restrict__ rowstart,
    int* __restrict__ blocksum, int* __restrict__ done) {
    __shared__ int sm[256];
    __shared__ int last;
    int t = threadIdx.x;
    int i = blockIdx.x * 256 + t;
    int v = (i < N_NODES) ? deg[i] : 0;
    sm[t] = v;
    __syncthreads();
    #pragma unroll
    for (int off = 1; off < 256; off <<= 1) {
        int x = (t >= off) ? sm[t - off] : 0;
        __syncthreads();
        sm[t] += x;
        __syncthreads();
    }
    if (i < N_NODES) rowstart[i] = sm[t] - v;  // exclusive within chunk
    if (t == 255) blocksum[blockIdx.x] = sm[t];
    // --- last-arriving block performs the chunk-total exclusive scan ---
    __threadfence();   // each thread: make own stores device-visible
    __syncthreads();   // all block stores fenced before the ticket
    if (t == 0) {
        int prev = __hip_atomic_fetch_add(done, 1, __ATOMIC_ACQ_REL,
                                          __HIP_MEMORY_SCOPE_AGENT);
        last = (prev == NBLK - 1) ? 1 : 0;
    }
    __syncthreads();
    if (!last) return;
    // per-thread acquire so stale cached blocksum lines are invalidated
    (void)__hip_atomic_load(done, __ATOMIC_ACQUIRE, __HIP_MEMORY_SCOPE_AGENT);
    int bv = (t < NBLK) ? blocksum[t] : 0;
    sm[t] = bv;
    __syncthreads();
    #pragma unroll
    for (int off = 1; off < 256; off <<= 1) {
        int x = (t >= off) ? sm[t - off] : 0;
        __syncthreads();
        sm[t] += x;
        __syncthreads();
    }
    if (t < NBLK) blocksum[t] = sm[t] - bv;  // exclusive prefix of totals
}

// ---- K3: bucket edge sources by destination (CSR fill) ----
__global__ void k_bucket(const int* __restrict__ esrc, const int* __restrict__ edst,
                         const int* __restrict__ rowstart, const int* __restrict__ blocksum,
                         int* __restrict__ cursor, int* __restrict__ csr_src) {
    int e = blockIdx.x * 256 + threadIdx.x;
    if (e >= N_EDGES) return;
    int d = edst[e];
    int pos = __hip_atomic_fetch_add(&cursor[d], 1, __ATOMIC_RELAXED, __HIP_MEMORY_SCOPE_AGENT);
    csr_src[rowstart[d] + blocksum[d >> 8] + pos] = esrc[e];
}

// ---- K4: gather: A[n][0:128] = bf16(avg of node_t rows in CSR row n) ----
__global__ __launch_bounds__(256) void k_gather(
    const int* __restrict__ csr_src, const int* __restrict__ rowstart,
    const int* __restrict__ blocksum, const int* __restrict__ deg,
    const unsigned short* __restrict__ node_t, unsigned short* __restrict__ A) {
    int n = blockIdx.x * 4 + (threadIdx.x >> 6);
    int lane = threadIdx.x & 63;
    int begin = rowstart[n] + blocksum[n >> 8];
    int cnt = deg[n];
    float a0 = 0.f, a1 = 0.f, b0 = 0.f, b1 = 0.f;
    float c0 = 0.f, c1 = 0.f, d0 = 0.f, d1 = 0.f;
    for (int base = 0; base < cnt; base += 64) {
        int rem = cnt - base;
        int m = rem < 64 ? rem : 64;
        int my = csr_src[begin + base + (lane < m ? lane : m - 1)];
        for (int i = 0; i < m; i += 8) {
            // masked parallel batch of 8: all loads issued (clamped index),
            // out-of-range contributions predicated to 0 — kills the serial
            // dependent-load tail (avg deg = 12.5).
            int i1 = i + 1 < m ? i + 1 : m - 1;
            int i2 = i + 2 < m ? i + 2 : m - 1;
            int i3 = i + 3 < m ? i + 3 : m - 1;
            int i4 = i + 4 < m ? i + 4 : m - 1;
            int i5 = i + 5 < m ? i + 5 : m - 1;
            int i6 = i + 6 < m ? i + 6 : m - 1;
            int i7 = i + 7 < m ? i + 7 : m - 1;
            int s0 = __shfl(my, i, 64),  s1 = __shfl(my, i1, 64);
            int s2 = __shfl(my, i2, 64), s3 = __shfl(my, i3, 64);
            int s4 = __shfl(my, i4, 64), s5 = __shfl(my, i5, 64);
            int s6 = __shfl(my, i6, 64), s7 = __shfl(my, i7, 64);
            unsigned u0 = *(const unsigned*)&node_t[s0 * DIM + lane * 2];
            unsigned u1 = *(const unsigned*)&node_t[s1 * DIM + lane * 2];
            unsigned u2 = *(const unsigned*)&node_t[s2 * DIM + lane * 2];
            unsigned u3 = *(const unsigned*)&node_t[s3 * DIM + lane * 2];
            unsigned u4 = *(const unsigned*)&node_t[s4 * DIM + lane * 2];
            unsigned u5 = *(const unsigned*)&node_t[s5 * DIM + lane * 2];
            unsigned u6 = *(const unsigned*)&node_t[s6 * DIM + lane * 2];
            unsigned u7 = *(const unsigned*)&node_t[s7 * DIM + lane * 2];
            a0 += lo_bf(u0); a1 += hi_bf(u0);
            b0 += (i + 1 < m) ? lo_bf(u1) : 0.f; b1 += (i + 1 < m) ? hi_bf(u1) : 0.f;
            c0 += (i + 2 < m) ? lo_bf(u2) : 0.f; c1 += (i + 2 < m) ? hi_bf(u2) : 0.f;
            d0 += (i + 3 < m) ? lo_bf(u3) : 0.f; d1 += (i + 3 < m) ? hi_bf(u3) : 0.f;
            a0 += (i + 4 < m) ? lo_bf(u4) : 0.f; a1 += (i + 4 < m) ? hi_bf(u4) : 0.f;
            b0 += (i + 5 < m) ? lo_bf(u5) : 0.f; b1 += (i + 5 < m) ? hi_bf(u5) : 0.f;
            c0 += (i + 6 < m) ? lo_bf(u6) : 0.f; c1 += (i + 6 < m) ? hi_bf(u6) : 0.f;
            d0 += (i + 7 < m) ? lo_bf(u7) : 0.f; d1 += (i + 7 < m) ? hi_bf(u7) : 0.f;
        }
    }
    float t0 = (a0 + b0) + (c0 + d0);
    float t1 = (a1 + b1) + (c1 + d1);
    float inv = (cnt > 0) ? 1.0f / (float)cnt : 0.0f;
    unsigned short o0 = f2bf(t0 * inv), o1 = f2bf(t1 * inv);
    *(unsigned*)&A[n * 512 + lane * 2] = (unsigned)o0 | ((unsigned)o1 << 16);
}

// ---- K5: [N x 512] @ [512 x 128] bf16 MFMA GEMM + expmap0 epilogue ----
// BK=64 double-buffered 2-phase pipeline (T3 minimum template).
#define RB 64
#define BK 64
__global__ __launch_bounds__(256) void k_gemm(
    const unsigned short* __restrict__ A, const int* __restrict__ deg,
    const unsigned short* __restrict__ Wt,  // [128][512] bf16
    const float* __restrict__ lin_b, const float* __restrict__ conv_b,
    const float* __restrict__ curv, float* __restrict__ out) {
    __shared__ __align__(16) unsigned short As[2][RB * BK];    // 8 KB each
    __shared__ __align__(16) unsigned short Bs[2][128 * BK];   // 16 KB each
    int tid = threadIdx.x;
    int n0 = blockIdx.x * RB;
    int w = tid >> 6;
    int lane = tid & 63;
    int ml = lane & 15;
    int q = lane >> 4;
    int lr = lane >> 3;      // row-within-8 for staging
    int lj = lane & 7;       // 16B-chunk-within-row for staging

    f32x4 acc[8];
    #pragma unroll
    for (int i = 0; i < 8; ++i) acc[i] = (f32x4){0.f, 0.f, 0.f, 0.f};

    // prologue: stage chunk 0 into buffer 0
    #pragma unroll
    for (int t = 0; t < 2; ++t) {
        int m = t * 4 + w;
        int r = m * 8 + lr;
        int jg = lj ^ (r & 7);
        gload_lds16(A + (n0 + r) * 512 + jg * 8, &As[0][m * 512]);
    }
    #pragma unroll
    for (int t = 0; t < 4; ++t) {
        int m = t * 4 + w;
        int r = m * 8 + lr;
        int jg = lj ^ (r & 7);
        gload_lds16(Wt + r * 512 + jg * 8, &Bs[0][m * 512]);
    }

    #pragma unroll
    for (int kk = 0; kk < 8; ++kk) {
        int cur = kk & 1;
        __syncthreads();  // drains stage-kk loads; all waves done with other buf
        if (kk < 7) {
            int nb = cur ^ 1;
            #pragma unroll
            for (int t = 0; t < 2; ++t) {
                int m = t * 4 + w;
                int r = m * 8 + lr;
                int jg = lj ^ (r & 7);
                gload_lds16(A + (n0 + r) * 512 + (kk + 1) * 64 + jg * 8, &As[nb][m * 512]);
            }
            #pragma unroll
            for (int t = 0; t < 4; ++t) {
                int m = t * 4 + w;
                int r = m * 8 + lr;
                int jg = lj ^ (r & 7);
                gload_lds16(Wt + r * 512 + (kk + 1) * 64 + jg * 8, &Bs[nb][m * 512]);
            }
        }
        __builtin_amdgcn_s_setprio(1);
        #pragma unroll
        for (int ks = 0; ks < 2; ++ks) {
            int ca = ((ks * 4 + q) ^ (ml & 7)) * 8;
            s16x8 a = *(const s16x8*)&As[cur][(w * 16 + ml) * BK + ca];
            #pragma unroll
            for (int ct = 0; ct < 8; ++ct) {
                s16x8 bb = *(const s16x8*)&Bs[cur][(ct * 16 + ml) * BK + ca];
                acc[ct] = __builtin_amdgcn_mfma_f32_16x16x32_bf16(a, bb, acc[ct], 0, 0, 0);
            }
        }
        __builtin_amdgcn_s_setprio(0);
    }

    float c = fabsf(curv[0]);
    float sc = sqrtf(c);
    float cb[8], lb[8];
    #pragma unroll
    for (int ct = 0; ct < 8; ++ct) {
        cb[ct] = conv_b[ct * 16 + ml];
        lb[ct] = lin_b[ct * 16 + ml];
    }
    #pragma unroll
    for (int r = 0; r < 4; ++r) {
        int n = n0 + w * 16 + q * 4 + r;  // D-frag: row = quad*4 + reg, col = lane&15
        bool valid = (n < N_NODES);
        float dgf = 0.f;
        if (valid) dgf = (deg[n] > 0) ? 1.0f : 0.0f;
        float y[8];
        float ssq = 0.f;
        #pragma unroll
        for (int ct = 0; ct < 8; ++ct) {
            float v = acc[ct][r] + cb[ct] + dgf * lb[ct];
            y[ct] = v;
            ssq += v * v;
        }
        ssq += __shfl_xor(ssq, 1, 64);
        ssq += __shfl_xor(ssq, 2, 64);
        ssq += __shfl_xor(ssq, 4, 64);
        ssq += __shfl_xor(ssq, 8, 64);
        float un = fmaxf(sqrtf(ssq), 1e-15f);
        float z = sc * un;
        float os;
        if (z < 0.25f) {
            float z2 = z * z;
            os = 1.0f + z2 * (-0.33333333f + z2 * (0.13333333f - z2 * 0.053968254f));
        } else {
            os = tanhf(z) / z;
        }
        if (valid) {
            #pragma unroll
            for (int ct = 0; ct < 8; ++ct)
                out[n * DIM + ct * 16 + ml] = y[ct] * os;  // f32 output
        }
    }
}

extern "C" void kernel_launch(void* const* d_in, const int* in_sizes, int n_in,
                              void* d_out, int out_size, void* d_ws, size_t ws_size,
                              hipStream_t stream) {
    (void)in_sizes; (void)n_in; (void)out_size; (void)ws_size;
    const float* node   = (const float*)d_in[0];
    const float* h1     = (const float*)d_in[1];
    const float* h2     = (const float*)d_in[2];
    const float* h3     = (const float*)d_in[3];
    const float* lin_w  = (const float*)d_in[4];
    const float* lin_b  = (const float*)d_in[5];
    const float* conv_w = (const float*)d_in[6];
    const float* conv_b = (const float*)d_in[7];
    const float* curv   = (const float*)d_in[8];
    const int* esrc = (const int*)d_in[9];
    const int* edst = (const int*)d_in[10];
    float* out = (float*)d_out;

    // ws layout (bytes):
    //   [0, 51,249,152)           A        bf16 [50048][512]
    //   [51,249,152, 64,049,152)  node_t   bf16 [N][128]
    //   [64,049,152, 64,180,224)  Wt       bf16 [128][512]
    //   [64,180,224, 64,380,224)  deg      i32 [N]   } adjacent: zeroed as one
    //   [64,380,224, 64,580,224)  cursor   i32 [N]   } range (100,001 ints)
    //   [64,580,224, 64,580,228)  done     i32 [1]   }
    //   [64,580,240, 64,780,240)  rowstart i32 [N]
    //   [64,780,240, 67,280,240)  csr_src  i32 [E]
    //   [67,280,240, 67,281,264)  blocksum i32 [256]
    char* ws = (char*)d_ws;
    unsigned short* A = (unsigned short*)ws;
    unsigned short* node_t = (unsigned short*)(ws + 51249152);
    unsigned short* Wt = (unsigned short*)(ws + 64049152);
    int* deg = (int*)(ws + 64180224);
    int* cursor = (int*)(ws + 64380224);
    int* done = (int*)(ws + 64580224);
    int* rowstart = (int*)(ws + 64580240);
    int* csr_src = (int*)(ws + 64780240);
    int* blocksum = (int*)(ws + 67280240);

    hipLaunchKernelGGL(k_zero, dim3(392), dim3(256), 0, stream, deg);
    hipLaunchKernelGGL(k_setup_hist, dim3(SH_BLOCKS), dim3(256), 0, stream,
                       node, h1, h2, h3, lin_w, conv_w, curv, edst,
                       node_t, A, Wt, deg);
    hipLaunchKernelGGL(k_scan12, dim3(NBLK), dim3(256), 0, stream,
                       deg, rowstart, blocksum, done);
    hipLaunchKernelGGL(k_bucket, dim3(EBLK), dim3(256), 0, stream,
                       esrc, edst, rowstart, blocksum, cursor, csr_src);
    hipLaunchKernelGGL(k_gather, dim3(12500), dim3(256), 0, stream,
                       csr_src, rowstart, blocksum, deg, node_t, A);
    hipLaunchKernelGGL(k_gemm, dim3((N_NODES + RB - 1) / RB), dim3(256), 0, stream,
                       A, deg, Wt, lin_b, conv_b, curv, out);
}

// Round 4
// 280.406 us; speedup vs baseline: 4.0178x; 1.0040x over previous
//
#include <hip/hip_runtime.h>

#define N_NODES 50000
#define DIM 128
#define N_EDGES 625000
#define NBLK 196   // ceil(N/256) scan blocks
#define EBLK 2442  // ceil(E/256) edge blocks

// k_setup grid partition: scale rows | W-pack | zero(deg4+done)
#define SC_BLOCKS 12500           // 16 rows/block over 4N rows
#define PK_BLOCKS 256             // W-pack: 65536 elems
#define ZR_BLOCKS 782             // zero deg4[4][N]+done = 200,001 ints
#define SETUP_BLOCKS (SC_BLOCKS + PK_BLOCKS + ZR_BLOCKS)

typedef float f32x4 __attribute__((ext_vector_type(4)));
typedef short s16x8 __attribute__((ext_vector_type(8)));

union U8 { unsigned short us[8]; uint4 v; };

__device__ __forceinline__ unsigned short f2bf(float f) {
    unsigned u = __builtin_bit_cast(unsigned, f);
    unsigned r = (u + 0x7fffu + ((u >> 16) & 1u)) >> 16;  // RNE
    return (unsigned short)r;
}
__device__ __forceinline__ float lo_bf(unsigned u) {
    return __builtin_bit_cast(float, u << 16);
}
__device__ __forceinline__ float hi_bf(unsigned u) {
    return __builtin_bit_cast(float, u & 0xffff0000u);
}

// async global->LDS, 16 B per lane; lds dest = uniform base + lane*16 (m104)
__device__ __forceinline__ void gload_lds16(const unsigned short* g, unsigned short* l) {
    __builtin_amdgcn_global_load_lds(
        (const __attribute__((address_space(1))) void*)g,
        (__attribute__((address_space(3))) void*)l, 16, 0, 0);
}

// logmap0 scale factor for one row given sum-of-squares reduced across group
__device__ __forceinline__ float logmap_scale(float ss, float sc) {
    float xn = fmaxf(sqrtf(ss), 1e-15f);
    float arg = fminf(sc * xn, 1.0f - 1e-5f);
    // s = artanh(arg)/(sc*xn); for arg<0.25 the clip is inactive so the
    // division cancels: artanh(z)/z = 1 + z^2/3 + z^4/5 + z^6/7 (rel err ~2e-6)
    if (arg < 0.25f) {
        float z2 = arg * arg;
        return 1.0f + z2 * (0.33333333f + z2 * (0.2f + z2 * 0.14285715f));
    }
    float at = 0.5f * log1pf(2.0f * arg / (1.0f - arg));
    return at / (sc * xn);
}

// ---- K1: fused setup + pack + zero (all independent block ranges) ----
__global__ __launch_bounds__(256) void k_setup(
    const float* __restrict__ node, const float* __restrict__ h1,
    const float* __restrict__ h2, const float* __restrict__ h3,
    const float* __restrict__ lin_w, const float* __restrict__ conv_w,
    const float* __restrict__ curv,
    unsigned short* __restrict__ node_t, unsigned short* __restrict__ A,
    unsigned short* __restrict__ Wt, int* __restrict__ zero_base) {
    int b = blockIdx.x;
    int tid = threadIdx.x;
    if (b < SC_BLOCKS) {
        int row = b * 16 + (tid >> 4);  // [0, 4N); matrix index uniform per block
        int g = tid & 15;
        int a = row / N_NODES;
        int n = row - a * N_NODES;
        const float* src = (a == 0) ? node : (a == 1) ? h1 : (a == 2) ? h2 : h3;
        const float4* p = (const float4*)&src[n * DIM + g * 8];
        float4 x0 = p[0], x1 = p[1];
        float ss = x0.x * x0.x + x0.y * x0.y + x0.z * x0.z + x0.w * x0.w
                 + x1.x * x1.x + x1.y * x1.y + x1.z * x1.z + x1.w * x1.w;
        ss += __shfl_xor(ss, 1, 64);
        ss += __shfl_xor(ss, 2, 64);
        ss += __shfl_xor(ss, 4, 64);
        ss += __shfl_xor(ss, 8, 64);  // 16-lane group reduction
        float c = fabsf(curv[0]);
        float s = logmap_scale(ss, sqrtf(c));
        U8 u;
        u.us[0] = f2bf(x0.x * s); u.us[1] = f2bf(x0.y * s);
        u.us[2] = f2bf(x0.z * s); u.us[3] = f2bf(x0.w * s);
        u.us[4] = f2bf(x1.x * s); u.us[5] = f2bf(x1.y * s);
        u.us[6] = f2bf(x1.z * s); u.us[7] = f2bf(x1.w * s);
        if (a == 0) {  // branch uniform per block
            *(uint4*)&node_t[n * DIM + g * 8] = u.v;
        } else {
            *(uint4*)&A[n * 512 + a * 128 + g * 8] = u.v;
        }
    } else if (b < SC_BLOCKS + PK_BLOCKS) {
        int idx = (b - SC_BLOCKS) * 256 + tid;  // 65536
        int o = idx >> 9;
        int k = idx & 511;
        float v;
        if (k < 128) {
            v = lin_w[o * 128 + k];
        } else {
            int kk = (k - 128) >> 7;
            int i = (k - 128) & 127;
            v = conv_w[o * 384 + i * 3 + kk];
        }
        Wt[idx] = f2bf(v);
    } else {
        int i = (b - SC_BLOCKS - PK_BLOCKS) * 256 + tid;
        if (i < 200001) zero_base[i] = 0;  // deg4[4][N] + done, adjacent
    }
}

// ---- K2: sharded degree histogram (shard = blockIdx&3 -> 4x less line
// contention on the 625k agent atomics; same shard fn as k_bucket) ----
__global__ void k_hist(const int* __restrict__ edst, int* __restrict__ deg4) {
    int e = blockIdx.x * 256 + threadIdx.x;
    int sh = blockIdx.x & 3;
    if (e < N_EDGES)
        __hip_atomic_fetch_add(&deg4[sh * N_NODES + edst[e]], 1,
                               __ATOMIC_RELAXED, __HIP_MEMORY_SCOPE_AGENT);
}

// ---- K3: scan: sum shards -> deg; per-shard prefixes (u16); zero cursor4
// (aliases deg4); per-chunk exclusive scan; last block scans chunk totals ----
__global__ __launch_bounds__(256) void k_scan12(
    int* __restrict__ deg4, int* __restrict__ deg,
    unsigned* __restrict__ prefix4,  // [N] pairs of u32 = 4 u16 per node
    int* __restrict__ rowstart, int* __restrict__ blocksum,
    int* __restrict__ done) {
    __shared__ int sm[256];
    __shared__ int last;
    int t = threadIdx.x;
    int i = blockIdx.x * 256 + t;
    int v = 0;
    if (i < N_NODES) {
        int d0 = deg4[0 * N_NODES + i];
        int d1 = deg4[1 * N_NODES + i];
        int d2 = deg4[2 * N_NODES + i];
        int d3 = deg4[3 * N_NODES + i];
        v = d0 + d1 + d2 + d3;
        deg[i] = v;
        // prefix4[n*4+x] (u16): 0, d0, d0+d1, d0+d1+d2  (little-endian packing)
        prefix4[i * 2 + 0] = ((unsigned)d0 << 16);
        prefix4[i * 2 + 1] = (unsigned)(d0 + d1) | ((unsigned)(d0 + d1 + d2) << 16);
        // zero cursor4 in place (aliases deg4) for k_bucket
        deg4[0 * N_NODES + i] = 0;
        deg4[1 * N_NODES + i] = 0;
        deg4[2 * N_NODES + i] = 0;
        deg4[3 * N_NODES + i] = 0;
    }
    sm[t] = v;
    __syncthreads();
    #pragma unroll
    for (int off = 1; off < 256; off <<= 1) {
        int x = (t >= off) ? sm[t - off] : 0;
        __syncthreads();
        sm[t] += x;
        __syncthreads();
    }
    if (i < N_NODES) rowstart[i] = sm[t] - v;  // exclusive within chunk
    if (t == 255) blocksum[blockIdx.x] = sm[t];
    // --- last-arriving block performs the chunk-total exclusive scan ---
    __threadfence();   // make all block stores device-visible
    __syncthreads();
    if (t == 0) {
        int prev = __hip_atomic_fetch_add(done, 1, __ATOMIC_ACQ_REL,
                                          __HIP_MEMORY_SCOPE_AGENT);
        last = (prev == NBLK - 1) ? 1 : 0;
    }
    __syncthreads();
    if (!last) return;
    (void)__hip_atomic_load(done, __ATOMIC_ACQUIRE, __HIP_MEMORY_SCOPE_AGENT);
    int bv = (t < NBLK) ? blocksum[t] : 0;
    sm[t] = bv;
    __syncthreads();
    #pragma unroll
    for (int off = 1; off < 256; off <<= 1) {
        int x = (t >= off) ? sm[t - off] : 0;
        __syncthreads();
        sm[t] += x;
        __syncthreads();
    }
    if (t < NBLK) blocksum[t] = sm[t] - bv;  // exclusive prefix of totals
}

// ---- K4: bucket edge sources by destination (sharded CSR fill, u16) ----
__global__ void k_bucket(const int* __restrict__ esrc, const int* __restrict__ edst,
                         const int* __restrict__ rowstart, const int* __restrict__ blocksum,
                         const unsigned short* __restrict__ prefix4,
                         int* __restrict__ cursor4, unsigned short* __restrict__ csr_src) {
    int e = blockIdx.x * 256 + threadIdx.x;
    if (e >= N_EDGES) return;
    int sh = blockIdx.x & 3;   // same shard fn as k_hist -> counts match
    int d = edst[e];
    int pos = __hip_atomic_fetch_add(&cursor4[sh * N_NODES + d], 1,
                                     __ATOMIC_RELAXED, __HIP_MEMORY_SCOPE_AGENT);
    int off = rowstart[d] + blocksum[d >> 8] + (int)prefix4[d * 4 + sh] + pos;
    csr_src[off] = (unsigned short)esrc[e];
}

// ---- K5: gather: A[n][0:128] = bf16(avg of node_t rows in CSR row n) ----
__global__ __launch_bounds__(256) void k_gather(
    const unsigned short* __restrict__ csr_src, const int* __restrict__ rowstart,
    const int* __restrict__ blocksum, const int* __restrict__ deg,
    const unsigned short* __restrict__ node_t, unsigned short* __restrict__ A) {
    int n = blockIdx.x * 4 + (threadIdx.x >> 6);
    int lane = threadIdx.x & 63;
    int begin = rowstart[n] + blocksum[n >> 8];
    int cnt = deg[n];
    float a0 = 0.f, a1 = 0.f, b0 = 0.f, b1 = 0.f;
    float c0 = 0.f, c1 = 0.f, d0 = 0.f, d1 = 0.f;
    for (int base = 0; base < cnt; base += 64) {
        int rem = cnt - base;
        int m = rem < 64 ? rem : 64;
        int my = (int)csr_src[begin + base + (lane < m ? lane : m - 1)];
        for (int i = 0; i < m; i += 8) {
            // masked parallel batch of 8: all loads issued (clamped index),
            // out-of-range contributions predicated to 0.
            int i1 = i + 1 < m ? i + 1 : m - 1;
            int i2 = i + 2 < m ? i + 2 : m - 1;
            int i3 = i + 3 < m ? i + 3 : m - 1;
            int i4 = i + 4 < m ? i + 4 : m - 1;
            int i5 = i + 5 < m ? i + 5 : m - 1;
            int i6 = i + 6 < m ? i + 6 : m - 1;
            int i7 = i + 7 < m ? i + 7 : m - 1;
            int s0 = __shfl(my, i, 64),  s1 = __shfl(my, i1, 64);
            int s2 = __shfl(my, i2, 64), s3 = __shfl(my, i3, 64);
            int s4 = __shfl(my, i4, 64), s5 = __shfl(my, i5, 64);
            int s6 = __shfl(my, i6, 64), s7 = __shfl(my, i7, 64);
            unsigned u0 = *(const unsigned*)&node_t[s0 * DIM + lane * 2];
            unsigned u1 = *(const unsigned*)&node_t[s1 * DIM + lane * 2];
            unsigned u2 = *(const unsigned*)&node_t[s2 * DIM + lane * 2];
            unsigned u3 = *(const unsigned*)&node_t[s3 * DIM + lane * 2];
            unsigned u4 = *(const unsigned*)&node_t[s4 * DIM + lane * 2];
            unsigned u5 = *(const unsigned*)&node_t[s5 * DIM + lane * 2];
            unsigned u6 = *(const unsigned*)&node_t[s6 * DIM + lane * 2];
            unsigned u7 = *(const unsigned*)&node_t[s7 * DIM + lane * 2];
            a0 += lo_bf(u0); a1 += hi_bf(u0);
            b0 += (i + 1 < m) ? lo_bf(u1) : 0.f; b1 += (i + 1 < m) ? hi_bf(u1) : 0.f;
            c0 += (i + 2 < m) ? lo_bf(u2) : 0.f; c1 += (i + 2 < m) ? hi_bf(u2) : 0.f;
            d0 += (i + 3 < m) ? lo_bf(u3) : 0.f; d1 += (i + 3 < m) ? hi_bf(u3) : 0.f;
            a0 += (i + 4 < m) ? lo_bf(u4) : 0.f; a1 += (i + 4 < m) ? hi_bf(u4) : 0.f;
            b0 += (i + 5 < m) ? lo_bf(u5) : 0.f; b1 += (i + 5 < m) ? hi_bf(u5) : 0.f;
            c0 += (i + 6 < m) ? lo_bf(u6) : 0.f; c1 += (i + 6 < m) ? hi_bf(u6) : 0.f;
            d0 += (i + 7 < m) ? lo_bf(u7) : 0.f; d1 += (i + 7 < m) ? hi_bf(u7) : 0.f;
        }
    }
    float t0 = (a0 + b0) + (c0 + d0);
    float t1 = (a1 + b1) + (c1 + d1);
    float inv = (cnt > 0) ? 1.0f / (float)cnt : 0.0f;
    unsigned short o0 = f2bf(t0 * inv), o1 = f2bf(t1 * inv);
    *(unsigned*)&A[n * 512 + lane * 2] = (unsigned)o0 | ((unsigned)o1 << 16);
}

// ---- K6: [N x 512] @ [512 x 128] bf16 MFMA GEMM + expmap0 epilogue ----
// BK=64 double-buffered 2-phase pipeline. Last block reads A rows >= N_NODES
// OOB into node_t region: garbage feeds only invalid rows, never written.
#define RB 64
#define BK 64
__global__ __launch_bounds__(256) void k_gemm(
    const unsigned short* __restrict__ A, const int* __restrict__ deg,
    const unsigned short* __restrict__ Wt,  // [128][512] bf16
    const float* __restrict__ lin_b, const float* __restrict__ conv_b,
    const float* __restrict__ curv, float* __restrict__ out) {
    __shared__ __align__(16) unsigned short As[2][RB * BK];    // 8 KB each
    __shared__ __align__(16) unsigned short Bs[2][128 * BK];   // 16 KB each
    int tid = threadIdx.x;
    int n0 = blockIdx.x * RB;
    int w = tid >> 6;
    int lane = tid & 63;
    int ml = lane & 15;
    int q = lane >> 4;
    int lr = lane >> 3;      // row-within-8 for staging
    int lj = lane & 7;       // 16B-chunk-within-row for staging

    f32x4 acc[8];
    #pragma unroll
    for (int i = 0; i < 8; ++i) acc[i] = (f32x4){0.f, 0.f, 0.f, 0.f};

    // prologue: stage chunk 0 into buffer 0
    #pragma unroll
    for (int t = 0; t < 2; ++t) {
        int m = t * 4 + w;
        int r = m * 8 + lr;
        int jg = lj ^ (r & 7);
        gload_lds16(A + (n0 + r) * 512 + jg * 8, &As[0][m * 512]);
    }
    #pragma unroll
    for (int t = 0; t < 4; ++t) {
        int m = t * 4 + w;
        int r = m * 8 + lr;
        int jg = lj ^ (r & 7);
        gload_lds16(Wt + r * 512 + jg * 8, &Bs[0][m * 512]);
    }

    #pragma unroll
    for (int kk = 0; kk < 8; ++kk) {
        int cur = kk & 1;
        __syncthreads();  // drains stage-kk loads; all waves done with other buf
        if (kk < 7) {
            int nb = cur ^ 1;
            #pragma unroll
            for (int t = 0; t < 2; ++t) {
                int m = t * 4 + w;
                int r = m * 8 + lr;
                int jg = lj ^ (r & 7);
                gload_lds16(A + (n0 + r) * 512 + (kk + 1) * 64 + jg * 8, &As[nb][m * 512]);
            }
            #pragma unroll
            for (int t = 0; t < 4; ++t) {
                int m = t * 4 + w;
                int r = m * 8 + lr;
                int jg = lj ^ (r & 7);
                gload_lds16(Wt + r * 512 + (kk + 1) * 64 + jg * 8, &Bs[nb][m * 512]);
            }
        }
        __builtin_amdgcn_s_setprio(1);
        #pragma unroll
        for (int ks = 0; ks < 2; ++ks) {
            int ca = ((ks * 4 + q) ^ (ml & 7)) * 8;
            s16x8 a = *(const s16x8*)&As[cur][(w * 16 + ml) * BK + ca];
            #pragma unroll
            for (int ct = 0; ct < 8; ++ct) {
                s16x8 bb = *(const s16x8*)&Bs[cur][(ct * 16 + ml) * BK + ca];
                acc[ct] = __builtin_amdgcn_mfma_f32_16x16x32_bf16(a, bb, acc[ct], 0, 0, 0);
            }
        }
        __builtin_amdgcn_s_setprio(0);
    }

    float c = fabsf(curv[0]);
    float sc = sqrtf(c);
    float cb[8], lb[8];
    #pragma unroll
    for (int ct = 0; ct < 8; ++ct) {
        cb[ct] = conv_b[ct * 16 + ml];
        lb[ct] = lin_b[ct * 16 + ml];
    }
    #pragma unroll
    for (int r = 0; r < 4; ++r) {
        int n = n0 + w * 16 + q * 4 + r;  // D-frag: row = quad*4 + reg, col = lane&15
        bool valid = (n < N_NODES);
        float dgf = 0.f;
        if (valid) dgf = (deg[n] > 0) ? 1.0f : 0.0f;
        float y[8];
        float ssq = 0.f;
        #pragma unroll
        for (int ct = 0; ct < 8; ++ct) {
            float v = acc[ct][r] + cb[ct] + dgf * lb[ct];
            y[ct] = v;
            ssq += v * v;
        }
        ssq += __shfl_xor(ssq, 1, 64);
        ssq += __shfl_xor(ssq, 2, 64);
        ssq += __shfl_xor(ssq, 4, 64);
        ssq += __shfl_xor(ssq, 8, 64);
        float un = fmaxf(sqrtf(ssq), 1e-15f);
        float z = sc * un;
        float os;
        if (z < 0.25f) {
            float z2 = z * z;
            os = 1.0f + z2 * (-0.33333333f + z2 * (0.13333333f - z2 * 0.053968254f));
        } else {
            os = tanhf(z) / z;
        }
        if (valid) {
            #pragma unroll
            for (int ct = 0; ct < 8; ++ct)
                out[n * DIM + ct * 16 + ml] = y[ct] * os;  // f32 output
        }
    }
}

extern "C" void kernel_launch(void* const* d_in, const int* in_sizes, int n_in,
                              void* d_out, int out_size, void* d_ws, size_t ws_size,
                              hipStream_t stream) {
    (void)in_sizes; (void)n_in; (void)out_size; (void)ws_size;
    const float* node   = (const float*)d_in[0];
    const float* h1     = (const float*)d_in[1];
    const float* h2     = (const float*)d_in[2];
    const float* h3     = (const float*)d_in[3];
    const float* lin_w  = (const float*)d_in[4];
    const float* lin_b  = (const float*)d_in[5];
    const float* conv_w = (const float*)d_in[6];
    const float* conv_b = (const float*)d_in[7];
    const float* curv   = (const float*)d_in[8];
    const int* esrc = (const int*)d_in[9];
    const int* edst = (const int*)d_in[10];
    float* out = (float*)d_out;

    // ws layout (bytes), total 66,982,100 (< previous 67,281,264 footprint):
    //   [0, 51,200,000)           A        bf16 [50000][512]
    //   [51,200,000, 64,000,000)  node_t   bf16 [N][128]
    //   [64,000,000, 64,131,072)  Wt       bf16 [128][512]
    //   [64,131,072, 64,931,072)  deg4     i32 [4][N]  (aliased as cursor4)
    //   [64,931,072, 64,931,076)  done     i32 [1]     } zeroed with deg4
    //   [64,931,076, 65,131,076)  deg      i32 [N]
    //   [65,131,076, 65,331,076)  rowstart i32 [N]
    //   [65,331,076, 65,731,076)  prefix4  u16 [N][4]
    //   [65,731,076, 66,981,076)  csr_src  u16 [E]
    //   [66,981,076, 66,982,100)  blocksum i32 [256]
    char* ws = (char*)d_ws;
    unsigned short* A = (unsigned short*)ws;
    unsigned short* node_t = (unsigned short*)(ws + 51200000);
    unsigned short* Wt = (unsigned short*)(ws + 64000000);
    int* deg4 = (int*)(ws + 64131072);
    int* done = (int*)(ws + 64931072);
    int* deg = (int*)(ws + 64931076);
    int* rowstart = (int*)(ws + 65131076);
    unsigned* prefix4 = (unsigned*)(ws + 65331076);
    unsigned short* csr_src = (unsigned short*)(ws + 65731076);
    int* blocksum = (int*)(ws + 66981076);

    hipLaunchKernelGGL(k_setup, dim3(SETUP_BLOCKS), dim3(256), 0, stream,
                       node, h1, h2, h3, lin_w, conv_w, curv,
                       node_t, A, Wt, deg4);
    hipLaunchKernelGGL(k_hist, dim3(EBLK), dim3(256), 0, stream, edst, deg4);
    hipLaunchKernelGGL(k_scan12, dim3(NBLK), dim3(256), 0, stream,
                       deg4, deg, prefix4, rowstart, blocksum, done);
    hipLaunchKernelGGL(k_bucket, dim3(EBLK), dim3(256), 0, stream,
                       esrc, edst, rowstart, blocksum,
                       (const unsigned short*)prefix4, deg4, csr_src);
    hipLaunchKernelGGL(k_gather, dim3(12500), dim3(256), 0, stream,
                       csr_src, rowstart, blocksum, deg, node_t, A);
    hipLaunchKernelGGL(k_gemm, dim3((N_NODES + RB - 1) / RB), dim3(256), 0, stream,
                       A, deg, Wt, lin_b, conv_b, curv, out);
}